// Round 6
// baseline (523.052 us; speedup 1.0000x reference)
//
#include <hip/hip_runtime.h>
#include <hip/hip_bf16.h>

// Clockwork RNN, hierarchical decomposition + bf16 MFMA GEMMs.
// Round 6: k_phase v4 — 2 waves/block (wave owns 64 rows = 4 M-tiles,
// 16 MFMAs as 4 independent 2-deep chains), distance-4 U prefetch with
// 4 rotating register slots, packed bf16 casts, raw lgkmcnt-only barrier.

#define TT 256
#define BB 128
#define INW 512
#define HH 128
#define MHW 1024

typedef __bf16 bf16x8 __attribute__((ext_vector_type(8)));
typedef __bf16 bf16x4 __attribute__((ext_vector_type(4)));
typedef float f32x4 __attribute__((ext_vector_type(4)));

__constant__ unsigned int c_hmod_off[8] = {
    0u, 4194304u, 6291456u, 7340032u, 7864320u, 8126464u, 8257536u, 8323072u};

__device__ __forceinline__ int active_thr(int t) {
    int ma = (t == 0) ? 8 : min(__ffs(t), 8);
    return ma * HH;
}

__device__ __forceinline__ unsigned short f2bf(float f) {
    union { float f; unsigned int u; } v{f};
    unsigned int r = v.u + 0x7FFFu + ((v.u >> 16) & 1u);  // RNE
    return (unsigned short)(r >> 16);
}
__device__ __forceinline__ unsigned int pack2(float lo, float hi) {
    return (unsigned int)f2bf(lo) | ((unsigned int)f2bf(hi) << 16);
}

#define TILE_B 16384  // one [128 rows][64 k] bf16 tile image in LDS

// Batch-load a [128][64] f32 tile: 8 independent float4 per thread.
__device__ __forceinline__ void stage_load(float4 (&v)[8],
                                           const float* __restrict__ src,
                                           int stride, int tid) {
    int k4 = (tid & 15) * 4;
    int r0 = tid >> 4;
#pragma unroll
    for (int p = 0; p < 8; ++p)
        v[p] = *reinterpret_cast<const float4*>(src + (size_t)(p * 16 + r0) * stride + k4);
}

// Convert + write the staged tile into LDS (bf16, XOR-swizzled rows).
__device__ __forceinline__ void stage_write(char* dst, const float4 (&v)[8], int tid) {
    int k8 = (tid & 15) * 8;  // byte offset of this thread's 4 bf16
    int r0 = tid >> 4;
#pragma unroll
    for (int p = 0; p < 8; ++p) {
        int row = p * 16 + r0;
        ushort4 b;
        b.x = f2bf(v[p].x); b.y = f2bf(v[p].y);
        b.z = f2bf(v[p].z); b.w = f2bf(v[p].w);
        int off = (row * 128 + k8) ^ ((row & 7) << 4);
        *reinterpret_cast<ushort4*>(dst + off) = b;
    }
}

// Read one 16x32 bf16 fragment (8 bf16) from a swizzled tile.
__device__ __forceinline__ bf16x8 frag_ld(const char* tile, int row, int ks, int lane) {
    int off = (row * 128 + ks * 64 + (lane >> 4) * 16) ^ ((row & 7) << 4);
    return *reinterpret_cast<const bf16x8*>(tile + off);
}

// 128x128x64 MFMA block: A-tile x B-tile -> acc
__device__ __forceinline__ void mfma_tile(const char* sA, const char* sB,
                                          f32x4 (&acc)[4][4], int lane,
                                          int wr, int wc) {
#pragma unroll
    for (int ks = 0; ks < 2; ++ks) {
        bf16x8 fa[4], fb[4];
#pragma unroll
        for (int i = 0; i < 4; ++i) {
            fa[i] = frag_ld(sA, wr + i * 16 + (lane & 15), ks, lane);
            fb[i] = frag_ld(sB, wc + i * 16 + (lane & 15), ks, lane);
        }
#pragma unroll
        for (int i = 0; i < 4; ++i)
#pragma unroll
            for (int j = 0; j < 4; ++j)
                acc[i][j] = __builtin_amdgcn_mfma_f32_16x16x32_bf16(
                    fa[i], fb[j], acc[i][j], 0, 0, 0);
    }
}

// ---------------------------------------------------------------------------
// K_xw: xwb[t][b][mi*H + r] = sum_i x[t][b][i]*Wxh[mi*H+r][i] + bh[...]
// ---------------------------------------------------------------------------
__global__ __launch_bounds__(256) void k_xw(const float* __restrict__ x,
                                            const float* __restrict__ Wxh,
                                            const float* __restrict__ bh,
                                            float* __restrict__ xwb) {
    int mi = blockIdx.x, t = blockIdx.y;
    if (mi * HH >= active_thr(t)) return;

    __shared__ char lds[4 * TILE_B];  // W0 X0 | W1 X1
    int tid = threadIdx.x, lane = tid & 63, wid = tid >> 6;
    int wr = (wid >> 1) * 64, wc = (wid & 1) * 64;
    const float* Wbase = Wxh + (size_t)(mi * HH) * INW;
    const float* Xbase = x + (size_t)t * BB * INW;

    f32x4 acc[4][4] = {};
    float4 vW[8], vX[8];
    stage_load(vW, Wbase, INW, tid);
    stage_load(vX, Xbase, INW, tid);
    stage_write(lds, vW, tid);
    stage_write(lds + TILE_B, vX, tid);

    for (int it = 0; it < 8; ++it) {
        int cur = it & 1;
        __syncthreads();
        if (it < 7) {
            stage_load(vW, Wbase + (it + 1) * 64, INW, tid);
            stage_load(vX, Xbase + (it + 1) * 64, INW, tid);
        }
        mfma_tile(lds + cur * 2 * TILE_B, lds + cur * 2 * TILE_B + TILE_B,
                  acc, lane, wr, wc);
        if (it < 7) {
            stage_write(lds + (cur ^ 1) * 2 * TILE_B, vW, tid);
            stage_write(lds + (cur ^ 1) * 2 * TILE_B + TILE_B, vX, tid);
        }
    }
#pragma unroll
    for (int i = 0; i < 4; ++i) {
        int rbase = wr + i * 16 + (lane >> 4) * 4;
        float4 bias = *reinterpret_cast<const float4*>(&bh[mi * HH + rbase]);
#pragma unroll
        for (int j = 0; j < 4; ++j) {
            int b = wc + j * 16 + (lane & 15);
            float4 v = make_float4(acc[i][j][0] + bias.x, acc[i][j][1] + bias.y,
                                   acc[i][j][2] + bias.z, acc[i][j][3] + bias.w);
            *reinterpret_cast<float4*>(
                &xwb[(size_t)(t * BB + b) * MHW + mi * HH + rbase]) = v;
        }
    }
}

// ---------------------------------------------------------------------------
// K_u: xwb[t][b][mi*H+r] += sum_{j>mi} Whh[mi*H+r][j*H+c] * h_j[b][c]
// ---------------------------------------------------------------------------
__global__ __launch_bounds__(256) void k_u(const float* __restrict__ Whh,
                                           const float* __restrict__ hprev,
                                           const float* __restrict__ hmod,
                                           float* __restrict__ xwb, int mi) {
    int k = blockIdx.x;
    int t = k << mi;
    __shared__ char lds[4 * TILE_B];  // A0 H0 | A1 H1
    int tid = threadIdx.x, lane = tid & 63, wid = tid >> 6;
    int wr = (wid >> 1) * 64, wc = (wid & 1) * 64;

    int ntile = 2 * (7 - mi);
    auto srcs = [&](int tt, const float*& pa, const float*& ph, int& hstr) {
        int j = mi + 1 + (tt >> 1);
        int c0 = (tt & 1) * 64;
        pa = Whh + (size_t)(mi * HH) * MHW + j * HH + c0;
        if (k == 0) {
            ph = hprev + j * HH + c0;
            hstr = MHW;
        } else {
            int g = (t - 1) >> j;
            ph = hmod + c_hmod_off[j] + (size_t)g * BB * HH + c0;
            hstr = HH;
        }
    };

    f32x4 acc[4][4] = {};
    float4 vA[8], vH[8];
    const float *pa, *ph;
    int hstr;
    srcs(0, pa, ph, hstr);
    stage_load(vA, pa, MHW, tid);
    stage_load(vH, ph, hstr, tid);
    stage_write(lds, vA, tid);
    stage_write(lds + TILE_B, vH, tid);

    for (int tt = 0; tt < ntile; ++tt) {
        int cur = tt & 1;
        __syncthreads();
        if (tt + 1 < ntile) {
            srcs(tt + 1, pa, ph, hstr);
            stage_load(vA, pa, MHW, tid);
            stage_load(vH, ph, hstr, tid);
        }
        mfma_tile(lds + cur * 2 * TILE_B, lds + cur * 2 * TILE_B + TILE_B,
                  acc, lane, wr, wc);
        if (tt + 1 < ntile) {
            stage_write(lds + (cur ^ 1) * 2 * TILE_B, vA, tid);
            stage_write(lds + (cur ^ 1) * 2 * TILE_B + TILE_B, vH, tid);
        }
    }
#pragma unroll
    for (int i = 0; i < 4; ++i) {
        int rbase = wr + i * 16 + (lane >> 4) * 4;
#pragma unroll
        for (int j = 0; j < 4; ++j) {
            int b = wc + j * 16 + (lane & 15);
            float4* p = reinterpret_cast<float4*>(
                &xwb[(size_t)(t * BB + b) * MHW + mi * HH + rbase]);
            float4 v = *p;
            v.x += acc[i][j][0]; v.y += acc[i][j][1];
            v.z += acc[i][j][2]; v.w += acc[i][j][3];
            *p = v;
        }
    }
}

// ---------------------------------------------------------------------------
// K_phase v4: MFMA scan, 2 waves/block. grid 8 blocks (16 batches each),
// 128 threads. Wave w owns rows [64w,64w+64) = 4 M-tiles; 16 MFMAs/step as
// 4 independent 2-deep chains. H ping-pongs through swizzled LDS; U
// prefetched distance 4 via 4 rotating register slots; lgkmcnt-only barrier
// (global loads/stores never drained in-loop). Tail steps padded to 4 with
// stores guarded.
// ---------------------------------------------------------------------------
__global__ __launch_bounds__(128) void k_phase(const float* __restrict__ Whh,
                                               const float* __restrict__ hprev,
                                               const float* __restrict__ xwb,
                                               float* __restrict__ hmod, int mi) {
    int b0 = blockIdx.x * 16;
    int tid = threadIdx.x, lane = tid & 63, wid = tid >> 6;
    int l15 = lane & 15, g = lane >> 4;
    __shared__ char sH[2][16 * 256];  // [buf][b][r*2 bytes], swizzled

    // --- A fragments Af[mm][kf]: rows r = 64*wid + mm*16 + l15 ---
    bf16x8 Af[4][4];
    {
        const float* Ab = Whh + (size_t)(mi * HH) * MHW + mi * HH;
#pragma unroll
        for (int mm = 0; mm < 4; ++mm) {
            const float* row = Ab + (size_t)(64 * wid + mm * 16 + l15) * MHW;
#pragma unroll
            for (int kf = 0; kf < 4; ++kf) {
                float4 v0 = *reinterpret_cast<const float4*>(row + kf * 32 + g * 8);
                float4 v1 = *reinterpret_cast<const float4*>(row + kf * 32 + g * 8 + 4);
                bf16x8 u;
                u[0] = (__bf16)v0.x; u[1] = (__bf16)v0.y;
                u[2] = (__bf16)v0.z; u[3] = (__bf16)v0.w;
                u[4] = (__bf16)v1.x; u[5] = (__bf16)v1.y;
                u[6] = (__bf16)v1.z; u[7] = (__bf16)v1.w;
                Af[mm][kf] = u;
            }
        }
    }
    // --- initial H into buf 0 (128 threads cover 16 batches x 128 rows) ---
#pragma unroll
    for (int p = 0; p < 2; ++p) {
        int tt = tid + p * 128;
        int b = tt >> 4, r8 = (tt & 15) * 8;
        const float* hp = hprev + (size_t)(b0 + b) * MHW + mi * HH + r8;
        float4 v0 = *reinterpret_cast<const float4*>(hp);
        float4 v1 = *reinterpret_cast<const float4*>(hp + 4);
        uint4 pk;
        pk.x = pack2(v0.x, v0.y); pk.y = pack2(v0.z, v0.w);
        pk.z = pack2(v1.x, v1.y); pk.w = pack2(v1.z, v1.w);
        int off = (b * 256 + r8 * 2) ^ ((b & 7) << 4);
        *reinterpret_cast<uint4*>(&sH[0][0] + off) = pk;
    }

    // per-lane constant offsets
    int roff[4], woff[4];
#pragma unroll
    for (int kf = 0; kf < 4; ++kf)
        roff[kf] = (l15 * 256 + kf * 64 + g * 16) ^ ((l15 & 7) << 4);
#pragma unroll
    for (int mm = 0; mm < 4; ++mm)
        woff[mm] = (l15 * 256 + (64 * wid + mm * 16 + g * 4) * 2) ^ ((l15 & 7) << 4);

    const float* xwb_lane = xwb + (size_t)(b0 + l15) * MHW + mi * HH + 64 * wid + g * 4;
    float* hmod_lane = hmod + c_hmod_off[mi] + (size_t)(b0 + l15) * HH + 64 * wid + g * 4;
    int Tm = TT >> mi;

    // U prefetch: 4 rotating slots, distance 4
    float4 uA[4], uB[4], uC[4], uD[4];
    {
        size_t s0 = 0;
        size_t s1 = (size_t)(min(1, Tm - 1) << mi) * BB * MHW;
        size_t s2 = (size_t)(min(2, Tm - 1) << mi) * BB * MHW;
        size_t s3 = (size_t)(min(3, Tm - 1) << mi) * BB * MHW;
#pragma unroll
        for (int mm = 0; mm < 4; ++mm) {
            uA[mm] = *reinterpret_cast<const float4*>(xwb_lane + s0 + mm * 16);
            uB[mm] = *reinterpret_cast<const float4*>(xwb_lane + s1 + mm * 16);
            uC[mm] = *reinterpret_cast<const float4*>(xwb_lane + s2 + mm * 16);
            uD[mm] = *reinterpret_cast<const float4*>(xwb_lane + s3 + mm * 16);
        }
    }
    __syncthreads();

// Raw barrier: LDS-visibility wait only; global loads/stores stay in flight.
#define SYNC_LDS()                                              \
    do {                                                        \
        asm volatile("s_waitcnt lgkmcnt(0)" ::: "memory");      \
        __builtin_amdgcn_sched_barrier(0);                      \
        __builtin_amdgcn_s_barrier();                           \
        __builtin_amdgcn_sched_barrier(0);                      \
    } while (0)

#define PHASE_STEP(KK, USLOT)                                                   \
    do {                                                                        \
        int cur = (KK) & 1;                                                     \
        bf16x8 Bf[4];                                                           \
        _Pragma("unroll") for (int kf = 0; kf < 4; ++kf)                        \
            Bf[kf] = *reinterpret_cast<const bf16x8*>(&sH[cur][0] + roff[kf]);  \
        f32x4 acc[4], acc2[4];                                                  \
        _Pragma("unroll") for (int mm = 0; mm < 4; ++mm) {                      \
            acc[mm][0] = USLOT[mm].x; acc[mm][1] = USLOT[mm].y;                 \
            acc[mm][2] = USLOT[mm].z; acc[mm][3] = USLOT[mm].w;                 \
            acc2[mm] = (f32x4){0.f, 0.f, 0.f, 0.f};                             \
        }                                                                       \
        size_t t2 = (size_t)(min((KK) + 4, Tm - 1) << mi) * BB * MHW;           \
        _Pragma("unroll") for (int mm = 0; mm < 4; ++mm)                        \
            USLOT[mm] = *reinterpret_cast<const float4*>(                       \
                xwb_lane + t2 + mm * 16);                                       \
        _Pragma("unroll") for (int mm = 0; mm < 4; ++mm) {                      \
            acc[mm] = __builtin_amdgcn_mfma_f32_16x16x32_bf16(                  \
                Af[mm][0], Bf[0], acc[mm], 0, 0, 0);                            \
            acc2[mm] = __builtin_amdgcn_mfma_f32_16x16x32_bf16(                 \
                Af[mm][2], Bf[2], acc2[mm], 0, 0, 0);                           \
            acc[mm] = __builtin_amdgcn_mfma_f32_16x16x32_bf16(                  \
                Af[mm][1], Bf[1], acc[mm], 0, 0, 0);                            \
            acc2[mm] = __builtin_amdgcn_mfma_f32_16x16x32_bf16(                 \
                Af[mm][3], Bf[3], acc2[mm], 0, 0, 0);                           \
        }                                                                       \
        _Pragma("unroll") for (int mm = 0; mm < 4; ++mm) {                      \
            acc[mm] += acc2[mm];                                                \
            bf16x4 pk;                                                          \
            pk[0] = (__bf16)acc[mm][0]; pk[1] = (__bf16)acc[mm][1];             \
            pk[2] = (__bf16)acc[mm][2]; pk[3] = (__bf16)acc[mm][3];             \
            *reinterpret_cast<bf16x4*>(&sH[cur ^ 1][0] + woff[mm]) = pk;        \
        }                                                                       \
        if ((KK) < Tm) {                                                        \
            _Pragma("unroll") for (int mm = 0; mm < 4; ++mm)                    \
                *reinterpret_cast<f32x4*>(                                      \
                    hmod_lane + (size_t)(KK)*BB * HH + mm * 16) = acc[mm];      \
        }                                                                       \
        SYNC_LDS();                                                             \
    } while (0)

    for (int k = 0; k < Tm; k += 4) {
        PHASE_STEP(k, uA);
        PHASE_STEP(k + 1, uB);
        PHASE_STEP(k + 2, uC);
        PHASE_STEP(k + 3, uD);
    }
#undef PHASE_STEP
#undef SYNC_LDS
}

// ---------------------------------------------------------------------------
// K_out: out[t][b][j*H + h] = Hmod[j][t>>j][b][h]; h_last for t==T-1
// ---------------------------------------------------------------------------
__global__ __launch_bounds__(256) void k_out(const float* __restrict__ hmod,
                                             float* __restrict__ out) {
    int b = blockIdx.x, t = blockIdx.y;
    int tid = threadIdx.x;
    int i = tid * 4;
    int j = i >> 7;
    int k = t >> j;
    const float4 v = *reinterpret_cast<const float4*>(
        &hmod[c_hmod_off[j] + ((size_t)k * BB + b) * HH + (i & 127)]);
    *reinterpret_cast<float4*>(&out[((size_t)t * BB + b) * MHW + i]) = v;
    if (t == TT - 1) {
        *reinterpret_cast<float4*>(
            &out[(size_t)TT * BB * MHW + (size_t)b * MHW + i]) = v;
    }
}

// ---------------------------------------------------------------------------
extern "C" void kernel_launch(void* const* d_in, const int* in_sizes, int n_in,
                              void* d_out, int out_size, void* d_ws, size_t ws_size,
                              hipStream_t stream) {
    const float* x = (const float*)d_in[0];
    const float* hprev = (const float*)d_in[1];
    const float* Wxh = (const float*)d_in[2];
    const float* Whh = (const float*)d_in[3];
    const float* bh = (const float*)d_in[4];
    float* out = (float*)d_out;

    float* xwb = out;            // scratch: xW + bh + u, overwritten by k_out
    float* hmod = (float*)d_ws;  // 8,355,840 floats = 33.4 MB

    k_xw<<<dim3(8, 256), 256, 0, stream>>>(x, Wxh, bh, xwb);

    for (int mi = 7; mi >= 0; --mi) {
        if (mi < 7)
            k_u<<<dim3(TT >> mi), 256, 0, stream>>>(Whh, hprev, hmod, xwb, mi);
        k_phase<<<8, 128, 0, stream>>>(Whh, hprev, xwb, hmod, mi);
    }

    k_out<<<dim3(128, 256), 256, 0, stream>>>(hmod, out);
}

// Round 8
// 500.856 us; speedup vs baseline: 1.0443x; 1.0443x over previous
//
#include <hip/hip_runtime.h>
#include <hip/hip_bf16.h>

// Clockwork RNN, hierarchical decomposition + bf16 MFMA GEMMs.
// Round 8: k_phase v6 — wave-specialized scan (producer/consumer):
//   waves 0-1: compute (LDS-only in loop: zero VMEM => zero compiler vmcnt)
//   wave 2:    u-producer, global_load_lds -> 8-slot LDS ring, counted
//              s_waitcnt vmcnt(24) (sound: no registers involved)
//   wave 3:    h-storer, drains sH ping-pong -> hmod (bf16) with ordinary
//              compiler-managed stores (its waits overlap compute)
// hmod is now bf16 (it feeds k_u's bf16 staging and k_out).

#define TT 256
#define BB 128
#define INW 512
#define HH 128
#define MHW 1024

typedef __bf16 bf16x8 __attribute__((ext_vector_type(8)));
typedef __bf16 bf16x4 __attribute__((ext_vector_type(4)));
typedef float f32x4 __attribute__((ext_vector_type(4)));

__constant__ unsigned int c_hmod_off[8] = {
    0u, 4194304u, 6291456u, 7340032u, 7864320u, 8126464u, 8257536u, 8323072u};

__device__ __forceinline__ int active_thr(int t) {
    int ma = (t == 0) ? 8 : min(__ffs(t), 8);
    return ma * HH;
}

__device__ __forceinline__ unsigned short f2bf(float f) {
    union { float f; unsigned int u; } v{f};
    unsigned int r = v.u + 0x7FFFu + ((v.u >> 16) & 1u);  // RNE
    return (unsigned short)(r >> 16);
}
__device__ __forceinline__ unsigned int pack2(float lo, float hi) {
    return (unsigned int)f2bf(lo) | ((unsigned int)f2bf(hi) << 16);
}
__device__ __forceinline__ float bf2f(unsigned short u) {
    union { unsigned int i; float f; } v;
    v.i = ((unsigned int)u) << 16;
    return v.f;
}

__device__ __forceinline__ void gld_lds16(const float* g, char* l) {
    __builtin_amdgcn_global_load_lds(
        (const __attribute__((address_space(1))) void*)g,
        (__attribute__((address_space(3))) void*)l, 16, 0, 0);
}

#define TILE_B 16384  // one [128 rows][64 k] bf16 tile image in LDS

// Batch-load a [128][64] f32 tile: 8 independent float4 per thread.
__device__ __forceinline__ void stage_load(float4 (&v)[8],
                                           const float* __restrict__ src,
                                           int stride, int tid) {
    int k4 = (tid & 15) * 4;
    int r0 = tid >> 4;
#pragma unroll
    for (int p = 0; p < 8; ++p)
        v[p] = *reinterpret_cast<const float4*>(src + (size_t)(p * 16 + r0) * stride + k4);
}

// Convert + write the staged tile into LDS (bf16, XOR-swizzled rows).
__device__ __forceinline__ void stage_write(char* dst, const float4 (&v)[8], int tid) {
    int k8 = (tid & 15) * 8;
    int r0 = tid >> 4;
#pragma unroll
    for (int p = 0; p < 8; ++p) {
        int row = p * 16 + r0;
        ushort4 b;
        b.x = f2bf(v[p].x); b.y = f2bf(v[p].y);
        b.z = f2bf(v[p].z); b.w = f2bf(v[p].w);
        int off = (row * 128 + k8) ^ ((row & 7) << 4);
        *reinterpret_cast<ushort4*>(dst + off) = b;
    }
}

// bf16-source variants: [128 rows][64 k] tile, row stride HH (ushorts).
__device__ __forceinline__ void stage_load_h16(uint4 (&v)[4],
                                               const unsigned short* __restrict__ src,
                                               int tid) {
    int k16 = (tid & 7) * 8;
    int r0 = tid >> 3;
#pragma unroll
    for (int p = 0; p < 4; ++p)
        v[p] = *reinterpret_cast<const uint4*>(src + (size_t)(p * 32 + r0) * HH + k16);
}
__device__ __forceinline__ void stage_write_h16(char* dst, const uint4 (&v)[4], int tid) {
    int k16 = (tid & 7) * 8;
    int r0 = tid >> 3;
#pragma unroll
    for (int p = 0; p < 4; ++p) {
        int row = p * 32 + r0;
        int off = (row * 128 + k16 * 2) ^ ((row & 7) << 4);
        *reinterpret_cast<uint4*>(dst + off) = v[p];
    }
}

// Read one 16x32 bf16 fragment (8 bf16) from a swizzled tile.
__device__ __forceinline__ bf16x8 frag_ld(const char* tile, int row, int ks, int lane) {
    int off = (row * 128 + ks * 64 + (lane >> 4) * 16) ^ ((row & 7) << 4);
    return *reinterpret_cast<const bf16x8*>(tile + off);
}

// 128x128x64 MFMA block: A-tile x B-tile -> acc
__device__ __forceinline__ void mfma_tile(const char* sA, const char* sB,
                                          f32x4 (&acc)[4][4], int lane,
                                          int wr, int wc) {
#pragma unroll
    for (int ks = 0; ks < 2; ++ks) {
        bf16x8 fa[4], fb[4];
#pragma unroll
        for (int i = 0; i < 4; ++i) {
            fa[i] = frag_ld(sA, wr + i * 16 + (lane & 15), ks, lane);
            fb[i] = frag_ld(sB, wc + i * 16 + (lane & 15), ks, lane);
        }
#pragma unroll
        for (int i = 0; i < 4; ++i)
#pragma unroll
            for (int j = 0; j < 4; ++j)
                acc[i][j] = __builtin_amdgcn_mfma_f32_16x16x32_bf16(
                    fa[i], fb[j], acc[i][j], 0, 0, 0);
    }
}

// ---------------------------------------------------------------------------
// K_xw: xwb[t][b][mi*H + r] = sum_i x[t][b][i]*Wxh[mi*H+r][i] + bh[...]
// ---------------------------------------------------------------------------
__global__ __launch_bounds__(256) void k_xw(const float* __restrict__ x,
                                            const float* __restrict__ Wxh,
                                            const float* __restrict__ bh,
                                            float* __restrict__ xwb) {
    int mi = blockIdx.x, t = blockIdx.y;
    if (mi * HH >= active_thr(t)) return;

    __shared__ char lds[4 * TILE_B];  // W0 X0 | W1 X1
    int tid = threadIdx.x, lane = tid & 63, wid = tid >> 6;
    int wr = (wid >> 1) * 64, wc = (wid & 1) * 64;
    const float* Wbase = Wxh + (size_t)(mi * HH) * INW;
    const float* Xbase = x + (size_t)t * BB * INW;

    f32x4 acc[4][4] = {};
    float4 vW[8], vX[8];
    stage_load(vW, Wbase, INW, tid);
    stage_load(vX, Xbase, INW, tid);
    stage_write(lds, vW, tid);
    stage_write(lds + TILE_B, vX, tid);

    for (int it = 0; it < 8; ++it) {
        int cur = it & 1;
        __syncthreads();
        if (it < 7) {
            stage_load(vW, Wbase + (it + 1) * 64, INW, tid);
            stage_load(vX, Xbase + (it + 1) * 64, INW, tid);
        }
        mfma_tile(lds + cur * 2 * TILE_B, lds + cur * 2 * TILE_B + TILE_B,
                  acc, lane, wr, wc);
        if (it < 7) {
            stage_write(lds + (cur ^ 1) * 2 * TILE_B, vW, tid);
            stage_write(lds + (cur ^ 1) * 2 * TILE_B + TILE_B, vX, tid);
        }
    }
#pragma unroll
    for (int i = 0; i < 4; ++i) {
        int rbase = wr + i * 16 + (lane >> 4) * 4;
        float4 bias = *reinterpret_cast<const float4*>(&bh[mi * HH + rbase]);
#pragma unroll
        for (int j = 0; j < 4; ++j) {
            int b = wc + j * 16 + (lane & 15);
            float4 v = make_float4(acc[i][j][0] + bias.x, acc[i][j][1] + bias.y,
                                   acc[i][j][2] + bias.z, acc[i][j][3] + bias.w);
            *reinterpret_cast<float4*>(
                &xwb[(size_t)(t * BB + b) * MHW + mi * HH + rbase]) = v;
        }
    }
}

// ---------------------------------------------------------------------------
// K_u: xwb[t][b][mi*H+r] += sum_{j>mi} Whh[mi*H+r][j*H+c] * h_j[b][c]
// H source: hprev f32 (k==0) else hmod bf16.
// ---------------------------------------------------------------------------
__global__ __launch_bounds__(256) void k_u(const float* __restrict__ Whh,
                                           const float* __restrict__ hprev,
                                           const unsigned short* __restrict__ hmod,
                                           float* __restrict__ xwb, int mi) {
    int k = blockIdx.x;
    int t = k << mi;
    __shared__ char lds[4 * TILE_B];  // A0 H0 | A1 H1
    int tid = threadIdx.x, lane = tid & 63, wid = tid >> 6;
    int wr = (wid >> 1) * 64, wc = (wid & 1) * 64;

    int ntile = 2 * (7 - mi);
    f32x4 acc[4][4] = {};

    if (k == 0) {
        auto srcs = [&](int tt, const float*& pa, const float*& ph) {
            int j = mi + 1 + (tt >> 1);
            int c0 = (tt & 1) * 64;
            pa = Whh + (size_t)(mi * HH) * MHW + j * HH + c0;
            ph = hprev + j * HH + c0;
        };
        float4 vA[8], vH[8];
        const float *pa, *ph;
        srcs(0, pa, ph);
        stage_load(vA, pa, MHW, tid);
        stage_load(vH, ph, MHW, tid);
        stage_write(lds, vA, tid);
        stage_write(lds + TILE_B, vH, tid);
        for (int tt = 0; tt < ntile; ++tt) {
            int cur = tt & 1;
            __syncthreads();
            if (tt + 1 < ntile) {
                srcs(tt + 1, pa, ph);
                stage_load(vA, pa, MHW, tid);
                stage_load(vH, ph, MHW, tid);
            }
            mfma_tile(lds + cur * 2 * TILE_B, lds + cur * 2 * TILE_B + TILE_B,
                      acc, lane, wr, wc);
            if (tt + 1 < ntile) {
                stage_write(lds + (cur ^ 1) * 2 * TILE_B, vA, tid);
                stage_write(lds + (cur ^ 1) * 2 * TILE_B + TILE_B, vH, tid);
            }
        }
    } else {
        auto srcs = [&](int tt, const float*& pa, const unsigned short*& ph) {
            int j = mi + 1 + (tt >> 1);
            int c0 = (tt & 1) * 64;
            pa = Whh + (size_t)(mi * HH) * MHW + j * HH + c0;
            int g = (t - 1) >> j;
            ph = hmod + c_hmod_off[j] + (size_t)g * BB * HH + c0;
        };
        float4 vA[8];
        uint4 vH[4];
        const float* pa;
        const unsigned short* ph;
        srcs(0, pa, ph);
        stage_load(vA, pa, MHW, tid);
        stage_load_h16(vH, ph, tid);
        stage_write(lds, vA, tid);
        stage_write_h16(lds + TILE_B, vH, tid);
        for (int tt = 0; tt < ntile; ++tt) {
            int cur = tt & 1;
            __syncthreads();
            if (tt + 1 < ntile) {
                srcs(tt + 1, pa, ph);
                stage_load(vA, pa, MHW, tid);
                stage_load_h16(vH, ph, tid);
            }
            mfma_tile(lds + cur * 2 * TILE_B, lds + cur * 2 * TILE_B + TILE_B,
                      acc, lane, wr, wc);
            if (tt + 1 < ntile) {
                stage_write(lds + (cur ^ 1) * 2 * TILE_B, vA, tid);
                stage_write_h16(lds + (cur ^ 1) * 2 * TILE_B + TILE_B, vH, tid);
            }
        }
    }
#pragma unroll
    for (int i = 0; i < 4; ++i) {
        int rbase = wr + i * 16 + (lane >> 4) * 4;
#pragma unroll
        for (int j = 0; j < 4; ++j) {
            int b = wc + j * 16 + (lane & 15);
            float4* p = reinterpret_cast<float4*>(
                &xwb[(size_t)(t * BB + b) * MHW + mi * HH + rbase]);
            float4 v = *p;
            v.x += acc[i][j][0]; v.y += acc[i][j][1];
            v.z += acc[i][j][2]; v.w += acc[i][j][3];
            *p = v;
        }
    }
}

// ---------------------------------------------------------------------------
// K_phase v6: wave-specialized MFMA scan. grid 8 blocks (16 batches each),
// 256 threads = waves {0,1}: compute, 2: u-producer, 3: h-storer.
// ---------------------------------------------------------------------------
#define SYNC_LDS()                                              \
    do {                                                        \
        asm volatile("s_waitcnt lgkmcnt(0)" ::: "memory");      \
        __builtin_amdgcn_sched_barrier(0);                      \
        __builtin_amdgcn_s_barrier();                           \
        __builtin_amdgcn_sched_barrier(0);                      \
    } while (0)
#define SYNC_VM24()                                             \
    do {                                                        \
        asm volatile("s_waitcnt vmcnt(24)" ::: "memory");       \
        __builtin_amdgcn_sched_barrier(0);                      \
        __builtin_amdgcn_s_barrier();                           \
        __builtin_amdgcn_sched_barrier(0);                      \
    } while (0)

__global__ __launch_bounds__(256) void k_phase(const float* __restrict__ Whh,
                                               const float* __restrict__ hprev,
                                               const float* __restrict__ xwb,
                                               unsigned short* __restrict__ hmod,
                                               int mi) {
    int b0 = blockIdx.x * 16;
    int tid = threadIdx.x, lane = tid & 63, wid = tid >> 6;
    int l15 = lane & 15, g = lane >> 4;
    __shared__ char sH[2][4096];   // [buf][b][r] bf16, swizzled
    __shared__ char sU[8][8192];   // u ring: [slot][c=r/4][b][4xf32], linear
    int Tm = TT >> mi;

    if (wid < 2) {
        // ================= compute waves =================
        bf16x8 Af[4][4];
        {
            const float* Ab = Whh + (size_t)(mi * HH) * MHW + mi * HH;
#pragma unroll
            for (int mm = 0; mm < 4; ++mm) {
                const float* row = Ab + (size_t)(64 * wid + mm * 16 + l15) * MHW;
#pragma unroll
                for (int kf = 0; kf < 4; ++kf) {
                    float4 v0 = *reinterpret_cast<const float4*>(row + kf * 32 + g * 8);
                    float4 v1 = *reinterpret_cast<const float4*>(row + kf * 32 + g * 8 + 4);
                    bf16x8 u;
                    u[0] = (__bf16)v0.x; u[1] = (__bf16)v0.y;
                    u[2] = (__bf16)v0.z; u[3] = (__bf16)v0.w;
                    u[4] = (__bf16)v1.x; u[5] = (__bf16)v1.y;
                    u[6] = (__bf16)v1.z; u[7] = (__bf16)v1.w;
                    Af[mm][kf] = u;
                }
            }
        }
        // initial H into buf 0 (tid 0..127 cover 16 batches x 128 rows)
#pragma unroll
        for (int p = 0; p < 2; ++p) {
            int tt = tid + p * 128;
            int b = tt >> 4, r8 = (tt & 15) * 8;
            const float* hp = hprev + (size_t)(b0 + b) * MHW + mi * HH + r8;
            float4 v0 = *reinterpret_cast<const float4*>(hp);
            float4 v1 = *reinterpret_cast<const float4*>(hp + 4);
            uint4 pk;
            pk.x = pack2(v0.x, v0.y); pk.y = pack2(v0.z, v0.w);
            pk.z = pack2(v1.x, v1.y); pk.w = pack2(v1.z, v1.w);
            int off = (b * 256 + r8 * 2) ^ ((b & 7) << 4);
            *reinterpret_cast<uint4*>(&sH[0][0] + off) = pk;
        }
        int roff[4], woff[4], uoff[4];
#pragma unroll
        for (int kf = 0; kf < 4; ++kf)
            roff[kf] = (l15 * 256 + kf * 64 + g * 16) ^ ((l15 & 7) << 4);
#pragma unroll
        for (int mm = 0; mm < 4; ++mm) {
            woff[mm] = (l15 * 256 + (64 * wid + mm * 16 + g * 4) * 2) ^ ((l15 & 7) << 4);
            uoff[mm] = (16 * wid + 4 * mm + g) * 256 + l15 * 16;
        }
        SYNC_LDS();

        for (int K = 0; K < Tm; ++K) {
            int cur = K & 1;
            const char* ub = &sU[K & 7][0];
            f32x4 acc[4], acc2[4];
#pragma unroll
            for (int mm = 0; mm < 4; ++mm) {
                acc[mm] = *reinterpret_cast<const f32x4*>(ub + uoff[mm]);
                acc2[mm] = (f32x4){0.f, 0.f, 0.f, 0.f};
            }
            bf16x8 Bf[4];
#pragma unroll
            for (int kf = 0; kf < 4; ++kf)
                Bf[kf] = *reinterpret_cast<const bf16x8*>(&sH[cur][0] + roff[kf]);
#pragma unroll
            for (int mm = 0; mm < 4; ++mm) {
                acc[mm] = __builtin_amdgcn_mfma_f32_16x16x32_bf16(
                    Af[mm][0], Bf[0], acc[mm], 0, 0, 0);
                acc2[mm] = __builtin_amdgcn_mfma_f32_16x16x32_bf16(
                    Af[mm][2], Bf[2], acc2[mm], 0, 0, 0);
                acc[mm] = __builtin_amdgcn_mfma_f32_16x16x32_bf16(
                    Af[mm][1], Bf[1], acc[mm], 0, 0, 0);
                acc2[mm] = __builtin_amdgcn_mfma_f32_16x16x32_bf16(
                    Af[mm][3], Bf[3], acc2[mm], 0, 0, 0);
            }
#pragma unroll
            for (int mm = 0; mm < 4; ++mm) {
                acc[mm] += acc2[mm];
                bf16x4 pk;
                pk[0] = (__bf16)acc[mm][0]; pk[1] = (__bf16)acc[mm][1];
                pk[2] = (__bf16)acc[mm][2]; pk[3] = (__bf16)acc[mm][3];
                *reinterpret_cast<bf16x4*>(&sH[cur ^ 1][0] + woff[mm]) = pk;
            }
            SYNC_LDS();
        }
    } else if (wid == 2) {
        // ================= u producer =================
        // position p = q*64 + lane -> c = p>>4 = q*4+g, b = l15
        // element offset = (c*4) within row; LDS linear dest.
        const float* ubase = xwb + (size_t)(b0 + l15) * MHW + mi * HH + g * 4;
#pragma unroll
        for (int q = 0; q < 4; ++q) {  // prologue: slots 0..3
            int t = min(q, Tm - 1) << mi;
            const float* pt = ubase + (size_t)t * BB * MHW;
#pragma unroll
            for (int p = 0; p < 8; ++p)
                gld_lds16(pt + p * 16, &sU[q][0] + p * 1024);
        }
        SYNC_VM24();  // retires slot 0
        for (int K = 0; K < Tm; ++K) {
            int t = min(K + 4, Tm - 1) << mi;
            int slot = (K + 4) & 7;
            const float* pt = ubase + (size_t)t * BB * MHW;
#pragma unroll
            for (int p = 0; p < 8; ++p)
                gld_lds16(pt + p * 16, &sU[slot][0] + p * 1024);
            SYNC_VM24();  // retires slot K+1 (needed next step)
        }
        asm volatile("s_waitcnt vmcnt(0)" ::: "memory");
    } else {
        // ================= h storer =================
        int bq = lane >> 2;
        int rr = (lane & 3) * 32;
        unsigned short* hm =
            hmod + c_hmod_off[mi] + (size_t)(b0 + bq) * HH + rr;
        int soff[4];
#pragma unroll
        for (int c = 0; c < 4; ++c)
            soff[c] = (bq * 256 + (rr + c * 8) * 2) ^ ((bq & 7) << 4);
        SYNC_LDS();
        for (int K = 0; K < Tm; ++K) {
            if (K >= 1) {
                uint4 h[4];
#pragma unroll
                for (int c = 0; c < 4; ++c)
                    h[c] = *reinterpret_cast<const uint4*>(&sH[K & 1][0] + soff[c]);
                unsigned short* dst = hm + (size_t)(K - 1) * BB * HH;
#pragma unroll
                for (int c = 0; c < 4; ++c)
                    *reinterpret_cast<uint4*>(dst + c * 8) = h[c];
            }
            SYNC_LDS();
        }
        {  // final state s_Tm -> hmod[Tm-1]
            uint4 h[4];
#pragma unroll
            for (int c = 0; c < 4; ++c)
                h[c] = *reinterpret_cast<const uint4*>(&sH[Tm & 1][0] + soff[c]);
            unsigned short* dst = hm + (size_t)(Tm - 1) * BB * HH;
#pragma unroll
            for (int c = 0; c < 4; ++c)
                *reinterpret_cast<uint4*>(dst + c * 8) = h[c];
        }
    }
}

// ---------------------------------------------------------------------------
// K_out: out[t][b][j*H + h] = bf2f(Hmod[j][t>>j][b][h]); h_last for t==T-1
// ---------------------------------------------------------------------------
__global__ __launch_bounds__(256) void k_out(const unsigned short* __restrict__ hmod,
                                             float* __restrict__ out) {
    int b = blockIdx.x, t = blockIdx.y;
    int tid = threadIdx.x;
    int i = tid * 4;
    int j = i >> 7;
    int k = t >> j;
    ushort4 h = *reinterpret_cast<const ushort4*>(
        &hmod[c_hmod_off[j] + ((size_t)k * BB + b) * HH + (i & 127)]);
    float4 v = make_float4(bf2f(h.x), bf2f(h.y), bf2f(h.z), bf2f(h.w));
    *reinterpret_cast<float4*>(&out[((size_t)t * BB + b) * MHW + i]) = v;
    if (t == TT - 1) {
        *reinterpret_cast<float4*>(
            &out[(size_t)TT * BB * MHW + (size_t)b * MHW + i]) = v;
    }
}

// ---------------------------------------------------------------------------
extern "C" void kernel_launch(void* const* d_in, const int* in_sizes, int n_in,
                              void* d_out, int out_size, void* d_ws, size_t ws_size,
                              hipStream_t stream) {
    const float* x = (const float*)d_in[0];
    const float* hprev = (const float*)d_in[1];
    const float* Wxh = (const float*)d_in[2];
    const float* Whh = (const float*)d_in[3];
    const float* bh = (const float*)d_in[4];
    float* out = (float*)d_out;

    float* xwb = out;                       // scratch: xW + bh + u
    unsigned short* hmod = (unsigned short*)d_ws;  // bf16, 16.7 MB

    k_xw<<<dim3(8, 256), 256, 0, stream>>>(x, Wxh, bh, xwb);

    for (int mi = 7; mi >= 0; --mi) {
        if (mi < 7)
            k_u<<<dim3(TT >> mi), 256, 0, stream>>>(Whh, hprev, hmod, xwb, mi);
        k_phase<<<8, 256, 0, stream>>>(Whh, hprev, xwb, hmod, mi);
    }

    k_out<<<dim3(128, 256), 256, 0, stream>>>(hmod, out);
}

// Round 9
// 483.360 us; speedup vs baseline: 1.0821x; 1.0362x over previous
//
#include <hip/hip_runtime.h>
#include <hip/hip_bf16.h>

// Clockwork RNN, hierarchical decomposition + bf16 MFMA GEMMs.
// Round 9: k_xw v2 — fused-mi blocks. One block per (batch-half, t):
//   x half-tile staged ONCE to LDS (bf16, 64KB); all active row-tiles
//   computed from it with W streamed via 16KB dbuf LDS tiles.
//   Bit-reversed t dispatch => heavy blocks (t=0,128) scheduled first.
// k_phase stays wave-specialized (R8); k_u/k_out unchanged.

#define TT 256
#define BB 128
#define INW 512
#define HH 128
#define MHW 1024

typedef __bf16 bf16x8 __attribute__((ext_vector_type(8)));
typedef __bf16 bf16x4 __attribute__((ext_vector_type(4)));
typedef float f32x4 __attribute__((ext_vector_type(4)));

__constant__ unsigned int c_hmod_off[8] = {
    0u, 4194304u, 6291456u, 7340032u, 7864320u, 8126464u, 8257536u, 8323072u};

__device__ __forceinline__ int active_thr(int t) {
    int ma = (t == 0) ? 8 : min(__ffs(t), 8);
    return ma * HH;
}

__device__ __forceinline__ unsigned short f2bf(float f) {
    union { float f; unsigned int u; } v{f};
    unsigned int r = v.u + 0x7FFFu + ((v.u >> 16) & 1u);  // RNE
    return (unsigned short)(r >> 16);
}
__device__ __forceinline__ unsigned int pack2(float lo, float hi) {
    return (unsigned int)f2bf(lo) | ((unsigned int)f2bf(hi) << 16);
}
__device__ __forceinline__ float bf2f(unsigned short u) {
    union { unsigned int i; float f; } v;
    v.i = ((unsigned int)u) << 16;
    return v.f;
}

__device__ __forceinline__ void gld_lds16(const float* g, char* l) {
    __builtin_amdgcn_global_load_lds(
        (const __attribute__((address_space(1))) void*)g,
        (__attribute__((address_space(3))) void*)l, 16, 0, 0);
}

#define TILE_B 16384  // one [128 rows][64 k] bf16 tile image in LDS

// Batch-load a [128][64] f32 tile: 8 independent float4 per thread.
__device__ __forceinline__ void stage_load(float4 (&v)[8],
                                           const float* __restrict__ src,
                                           int stride, int tid) {
    int k4 = (tid & 15) * 4;
    int r0 = tid >> 4;
#pragma unroll
    for (int p = 0; p < 8; ++p)
        v[p] = *reinterpret_cast<const float4*>(src + (size_t)(p * 16 + r0) * stride + k4);
}

// Convert + write the staged tile into LDS (bf16, XOR-swizzled rows).
__device__ __forceinline__ void stage_write(char* dst, const float4 (&v)[8], int tid) {
    int k8 = (tid & 15) * 8;
    int r0 = tid >> 4;
#pragma unroll
    for (int p = 0; p < 8; ++p) {
        int row = p * 16 + r0;
        ushort4 b;
        b.x = f2bf(v[p].x); b.y = f2bf(v[p].y);
        b.z = f2bf(v[p].z); b.w = f2bf(v[p].w);
        int off = (row * 128 + k8) ^ ((row & 7) << 4);
        *reinterpret_cast<ushort4*>(dst + off) = b;
    }
}

// 64-row chunk variants (x half-tile staging): [64][64] f32 -> 8KB bf16 tile.
__device__ __forceinline__ void stage_load64(float4 (&v)[4],
                                             const float* __restrict__ src,
                                             int stride, int tid) {
    int k4 = (tid & 15) * 4;
    int r0 = tid >> 4;
#pragma unroll
    for (int p = 0; p < 4; ++p)
        v[p] = *reinterpret_cast<const float4*>(src + (size_t)(p * 16 + r0) * stride + k4);
}
__device__ __forceinline__ void stage_write64(char* dst, const float4 (&v)[4], int tid) {
    int k8 = (tid & 15) * 8;
    int r0 = tid >> 4;
#pragma unroll
    for (int p = 0; p < 4; ++p) {
        int row = p * 16 + r0;
        ushort4 b;
        b.x = f2bf(v[p].x); b.y = f2bf(v[p].y);
        b.z = f2bf(v[p].z); b.w = f2bf(v[p].w);
        int off = (row * 128 + k8) ^ ((row & 7) << 4);
        *reinterpret_cast<ushort4*>(dst + off) = b;
    }
}

// bf16-source variants: [128 rows][64 k] tile, row stride HH (ushorts).
__device__ __forceinline__ void stage_load_h16(uint4 (&v)[4],
                                               const unsigned short* __restrict__ src,
                                               int tid) {
    int k16 = (tid & 7) * 8;
    int r0 = tid >> 3;
#pragma unroll
    for (int p = 0; p < 4; ++p)
        v[p] = *reinterpret_cast<const uint4*>(src + (size_t)(p * 32 + r0) * HH + k16);
}
__device__ __forceinline__ void stage_write_h16(char* dst, const uint4 (&v)[4], int tid) {
    int k16 = (tid & 7) * 8;
    int r0 = tid >> 3;
#pragma unroll
    for (int p = 0; p < 4; ++p) {
        int row = p * 32 + r0;
        int off = (row * 128 + k16 * 2) ^ ((row & 7) << 4);
        *reinterpret_cast<uint4*>(dst + off) = v[p];
    }
}

// Read one 16x32 bf16 fragment (8 bf16) from a swizzled tile.
__device__ __forceinline__ bf16x8 frag_ld(const char* tile, int row, int ks, int lane) {
    int off = (row * 128 + ks * 64 + (lane >> 4) * 16) ^ ((row & 7) << 4);
    return *reinterpret_cast<const bf16x8*>(tile + off);
}

// 128x128x64 MFMA block: A-tile x B-tile -> acc (4 waves, 64x64 quadrants)
__device__ __forceinline__ void mfma_tile(const char* sA, const char* sB,
                                          f32x4 (&acc)[4][4], int lane,
                                          int wr, int wc) {
#pragma unroll
    for (int ks = 0; ks < 2; ++ks) {
        bf16x8 fa[4], fb[4];
#pragma unroll
        for (int i = 0; i < 4; ++i) {
            fa[i] = frag_ld(sA, wr + i * 16 + (lane & 15), ks, lane);
            fb[i] = frag_ld(sB, wc + i * 16 + (lane & 15), ks, lane);
        }
#pragma unroll
        for (int i = 0; i < 4; ++i)
#pragma unroll
            for (int j = 0; j < 4; ++j)
                acc[i][j] = __builtin_amdgcn_mfma_f32_16x16x32_bf16(
                    fa[i], fb[j], acc[i][j], 0, 0, 0);
    }
}

// ---------------------------------------------------------------------------
// K_xw v2: one block per (half, t). x half-tile [64][512] staged once (bf16,
// 8 chunk-tiles of [64][64]); loop over nrt row-tiles x 8 k-chunks with W
// double-buffered. Output 128r x 64b per tile; bias added at tile epilogue.
// grid (2, 256), 256 threads (4 waves: wr in {0,64}, wc in {0,32}).
// ---------------------------------------------------------------------------
__global__ __launch_bounds__(256) void k_xw(const float* __restrict__ x,
                                            const float* __restrict__ Wxh,
                                            const float* __restrict__ bh,
                                            float* __restrict__ xwb) {
    int half = blockIdx.x;
    int y = blockIdx.y;  // bit-reverse => heavy t first
    int t = ((y & 1) << 7) | ((y & 2) << 5) | ((y & 4) << 3) | ((y & 8) << 1) |
            ((y & 16) >> 1) | ((y & 32) >> 3) | ((y & 64) >> 5) | ((y & 128) >> 7);
    int nrt = active_thr(t) >> 7;

    __shared__ char xl[8 * 8192];   // 64KB: x chunks [c][64b][64k] bf16
    __shared__ char sW[2 * TILE_B]; // 32KB: W dbuf
    int tid = threadIdx.x, lane = tid & 63, wid = tid >> 6;
    int l15 = lane & 15, g = lane >> 4;
    int wr = (wid >> 1) * 64, wc = (wid & 1) * 32;

    // --- stage x half-tile (8 chunks, reg-ping-pong) ---
    const float* Xb = x + ((size_t)t * BB + half * 64) * INW;
    {
        float4 va[4], vb[4];
        stage_load64(va, Xb, INW, tid);
#pragma unroll
        for (int c = 0; c < 8; ++c) {
            if (c & 1) {
                if (c < 7) stage_load64(va, Xb + (c + 1) * 64, INW, tid);
                stage_write64(xl + c * 8192, vb, tid);
            } else {
                if (c < 7) stage_load64(vb, Xb + (c + 1) * 64, INW, tid);
                stage_write64(xl + c * 8192, va, tid);
            }
        }
    }
    // --- W pipeline over nt = nrt*8 tile-iterations ---
    int nt = nrt * 8;
    float4 vW[8];
    stage_load(vW, Wxh, INW, tid);
    stage_write(sW, vW, tid);
    f32x4 acc[4][2] = {};

    for (int it = 0; it < nt; ++it) {
        int cur = it & 1;
        __syncthreads();
        if (it + 1 < nt) {
            int rt1 = (it + 1) >> 3, c1 = (it + 1) & 7;
            stage_load(vW, Wxh + (size_t)(rt1 * 128) * INW + c1 * 64, INW, tid);
        }
        const char* sA = sW + cur * TILE_B;
        const char* sB = xl + (it & 7) * 8192;
#pragma unroll
        for (int ks = 0; ks < 2; ++ks) {
            bf16x8 fa[4], fb[2];
#pragma unroll
            for (int i = 0; i < 4; ++i)
                fa[i] = frag_ld(sA, wr + i * 16 + l15, ks, lane);
#pragma unroll
            for (int j = 0; j < 2; ++j)
                fb[j] = frag_ld(sB, wc + j * 16 + l15, ks, lane);
#pragma unroll
            for (int i = 0; i < 4; ++i)
#pragma unroll
                for (int j = 0; j < 2; ++j)
                    acc[i][j] = __builtin_amdgcn_mfma_f32_16x16x32_bf16(
                        fa[i], fb[j], acc[i][j], 0, 0, 0);
        }
        if (it + 1 < nt) stage_write(sW + (cur ^ 1) * TILE_B, vW, tid);
        if ((it & 7) == 7) {  // row-tile epilogue
            int rt = it >> 3;
#pragma unroll
            for (int i = 0; i < 4; ++i) {
                int rbase = rt * 128 + wr + i * 16 + g * 4;
                float4 bias = *reinterpret_cast<const float4*>(&bh[rbase]);
#pragma unroll
                for (int j = 0; j < 2; ++j) {
                    int b = half * 64 + wc + j * 16 + l15;
                    float4 v = make_float4(acc[i][j][0] + bias.x,
                                           acc[i][j][1] + bias.y,
                                           acc[i][j][2] + bias.z,
                                           acc[i][j][3] + bias.w);
                    *reinterpret_cast<float4*>(
                        &xwb[(size_t)(t * BB + b) * MHW + rbase]) = v;
                    acc[i][j] = (f32x4){0.f, 0.f, 0.f, 0.f};
                }
            }
        }
    }
}

// ---------------------------------------------------------------------------
// K_u: xwb[t][b][mi*H+r] += sum_{j>mi} Whh[mi*H+r][j*H+c] * h_j[b][c]
// H source: hprev f32 (k==0) else hmod bf16.
// ---------------------------------------------------------------------------
__global__ __launch_bounds__(256) void k_u(const float* __restrict__ Whh,
                                           const float* __restrict__ hprev,
                                           const unsigned short* __restrict__ hmod,
                                           float* __restrict__ xwb, int mi) {
    int k = blockIdx.x;
    int t = k << mi;
    __shared__ char lds[4 * TILE_B];  // A0 H0 | A1 H1
    int tid = threadIdx.x, lane = tid & 63, wid = tid >> 6;
    int wr = (wid >> 1) * 64, wc = (wid & 1) * 64;

    int ntile = 2 * (7 - mi);
    f32x4 acc[4][4] = {};

    if (k == 0) {
        auto srcs = [&](int tt, const float*& pa, const float*& ph) {
            int j = mi + 1 + (tt >> 1);
            int c0 = (tt & 1) * 64;
            pa = Whh + (size_t)(mi * HH) * MHW + j * HH + c0;
            ph = hprev + j * HH + c0;
        };
        float4 vA[8], vH[8];
        const float *pa, *ph;
        srcs(0, pa, ph);
        stage_load(vA, pa, MHW, tid);
        stage_load(vH, ph, MHW, tid);
        stage_write(lds, vA, tid);
        stage_write(lds + TILE_B, vH, tid);
        for (int tt = 0; tt < ntile; ++tt) {
            int cur = tt & 1;
            __syncthreads();
            if (tt + 1 < ntile) {
                srcs(tt + 1, pa, ph);
                stage_load(vA, pa, MHW, tid);
                stage_load(vH, ph, MHW, tid);
            }
            mfma_tile(lds + cur * 2 * TILE_B, lds + cur * 2 * TILE_B + TILE_B,
                      acc, lane, wr, wc);
            if (tt + 1 < ntile) {
                stage_write(lds + (cur ^ 1) * 2 * TILE_B, vA, tid);
                stage_write(lds + (cur ^ 1) * 2 * TILE_B + TILE_B, vH, tid);
            }
        }
    } else {
        auto srcs = [&](int tt, const float*& pa, const unsigned short*& ph) {
            int j = mi + 1 + (tt >> 1);
            int c0 = (tt & 1) * 64;
            pa = Whh + (size_t)(mi * HH) * MHW + j * HH + c0;
            int g = (t - 1) >> j;
            ph = hmod + c_hmod_off[j] + (size_t)g * BB * HH + c0;
        };
        float4 vA[8];
        uint4 vH[4];
        const float* pa;
        const unsigned short* ph;
        srcs(0, pa, ph);
        stage_load(vA, pa, MHW, tid);
        stage_load_h16(vH, ph, tid);
        stage_write(lds, vA, tid);
        stage_write_h16(lds + TILE_B, vH, tid);
        for (int tt = 0; tt < ntile; ++tt) {
            int cur = tt & 1;
            __syncthreads();
            if (tt + 1 < ntile) {
                srcs(tt + 1, pa, ph);
                stage_load(vA, pa, MHW, tid);
                stage_load_h16(vH, ph, tid);
            }
            mfma_tile(lds + cur * 2 * TILE_B, lds + cur * 2 * TILE_B + TILE_B,
                      acc, lane, wr, wc);
            if (tt + 1 < ntile) {
                stage_write(lds + (cur ^ 1) * 2 * TILE_B, vA, tid);
                stage_write_h16(lds + (cur ^ 1) * 2 * TILE_B + TILE_B, vH, tid);
            }
        }
    }
#pragma unroll
    for (int i = 0; i < 4; ++i) {
        int rbase = wr + i * 16 + (lane >> 4) * 4;
#pragma unroll
        for (int j = 0; j < 4; ++j) {
            int b = wc + j * 16 + (lane & 15);
            float4* p = reinterpret_cast<float4*>(
                &xwb[(size_t)(t * BB + b) * MHW + mi * HH + rbase]);
            float4 v = *p;
            v.x += acc[i][j][0]; v.y += acc[i][j][1];
            v.z += acc[i][j][2]; v.w += acc[i][j][3];
            *p = v;
        }
    }
}

// ---------------------------------------------------------------------------
// K_phase v6: wave-specialized MFMA scan. grid 8 blocks (16 batches each),
// 256 threads = waves {0,1}: compute, 2: u-producer, 3: h-storer.
// ---------------------------------------------------------------------------
#define SYNC_LDS()                                              \
    do {                                                        \
        asm volatile("s_waitcnt lgkmcnt(0)" ::: "memory");      \
        __builtin_amdgcn_sched_barrier(0);                      \
        __builtin_amdgcn_s_barrier();                           \
        __builtin_amdgcn_sched_barrier(0);                      \
    } while (0)
#define SYNC_VM24()                                             \
    do {                                                        \
        asm volatile("s_waitcnt vmcnt(24)" ::: "memory");       \
        __builtin_amdgcn_sched_barrier(0);                      \
        __builtin_amdgcn_s_barrier();                           \
        __builtin_amdgcn_sched_barrier(0);                      \
    } while (0)

__global__ __launch_bounds__(256) void k_phase(const float* __restrict__ Whh,
                                               const float* __restrict__ hprev,
                                               const float* __restrict__ xwb,
                                               unsigned short* __restrict__ hmod,
                                               int mi) {
    int b0 = blockIdx.x * 16;
    int tid = threadIdx.x, lane = tid & 63, wid = tid >> 6;
    int l15 = lane & 15, g = lane >> 4;
    __shared__ char sH[2][4096];   // [buf][b][r] bf16, swizzled
    __shared__ char sU[8][8192];   // u ring: [slot][c=r/4][b][4xf32], linear
    int Tm = TT >> mi;

    if (wid < 2) {
        // ================= compute waves =================
        bf16x8 Af[4][4];
        {
            const float* Ab = Whh + (size_t)(mi * HH) * MHW + mi * HH;
#pragma unroll
            for (int mm = 0; mm < 4; ++mm) {
                const float* row = Ab + (size_t)(64 * wid + mm * 16 + l15) * MHW;
#pragma unroll
                for (int kf = 0; kf < 4; ++kf) {
                    float4 v0 = *reinterpret_cast<const float4*>(row + kf * 32 + g * 8);
                    float4 v1 = *reinterpret_cast<const float4*>(row + kf * 32 + g * 8 + 4);
                    bf16x8 u;
                    u[0] = (__bf16)v0.x; u[1] = (__bf16)v0.y;
                    u[2] = (__bf16)v0.z; u[3] = (__bf16)v0.w;
                    u[4] = (__bf16)v1.x; u[5] = (__bf16)v1.y;
                    u[6] = (__bf16)v1.z; u[7] = (__bf16)v1.w;
                    Af[mm][kf] = u;
                }
            }
        }
        // initial H into buf 0 (tid 0..127 cover 16 batches x 128 rows)
#pragma unroll
        for (int p = 0; p < 2; ++p) {
            int tt = tid + p * 128;
            int b = tt >> 4, r8 = (tt & 15) * 8;
            const float* hp = hprev + (size_t)(b0 + b) * MHW + mi * HH + r8;
            float4 v0 = *reinterpret_cast<const float4*>(hp);
            float4 v1 = *reinterpret_cast<const float4*>(hp + 4);
            uint4 pk;
            pk.x = pack2(v0.x, v0.y); pk.y = pack2(v0.z, v0.w);
            pk.z = pack2(v1.x, v1.y); pk.w = pack2(v1.z, v1.w);
            int off = (b * 256 + r8 * 2) ^ ((b & 7) << 4);
            *reinterpret_cast<uint4*>(&sH[0][0] + off) = pk;
        }
        int roff[4], woff[4], uoff[4];
#pragma unroll
        for (int kf = 0; kf < 4; ++kf)
            roff[kf] = (l15 * 256 + kf * 64 + g * 16) ^ ((l15 & 7) << 4);
#pragma unroll
        for (int mm = 0; mm < 4; ++mm) {
            woff[mm] = (l15 * 256 + (64 * wid + mm * 16 + g * 4) * 2) ^ ((l15 & 7) << 4);
            uoff[mm] = (16 * wid + 4 * mm + g) * 256 + l15 * 16;
        }
        SYNC_LDS();

        for (int K = 0; K < Tm; ++K) {
            int cur = K & 1;
            const char* ub = &sU[K & 7][0];
            f32x4 acc[4], acc2[4];
#pragma unroll
            for (int mm = 0; mm < 4; ++mm) {
                acc[mm] = *reinterpret_cast<const f32x4*>(ub + uoff[mm]);
                acc2[mm] = (f32x4){0.f, 0.f, 0.f, 0.f};
            }
            bf16x8 Bf[4];
#pragma unroll
            for (int kf = 0; kf < 4; ++kf)
                Bf[kf] = *reinterpret_cast<const bf16x8*>(&sH[cur][0] + roff[kf]);
#pragma unroll
            for (int mm = 0; mm < 4; ++mm) {
                acc[mm] = __builtin_amdgcn_mfma_f32_16x16x32_bf16(
                    Af[mm][0], Bf[0], acc[mm], 0, 0, 0);
                acc2[mm] = __builtin_amdgcn_mfma_f32_16x16x32_bf16(
                    Af[mm][2], Bf[2], acc2[mm], 0, 0, 0);
                acc[mm] = __builtin_amdgcn_mfma_f32_16x16x32_bf16(
                    Af[mm][1], Bf[1], acc[mm], 0, 0, 0);
                acc2[mm] = __builtin_amdgcn_mfma_f32_16x16x32_bf16(
                    Af[mm][3], Bf[3], acc2[mm], 0, 0, 0);
            }
#pragma unroll
            for (int mm = 0; mm < 4; ++mm) {
                acc[mm] += acc2[mm];
                bf16x4 pk;
                pk[0] = (__bf16)acc[mm][0]; pk[1] = (__bf16)acc[mm][1];
                pk[2] = (__bf16)acc[mm][2]; pk[3] = (__bf16)acc[mm][3];
                *reinterpret_cast<bf16x4*>(&sH[cur ^ 1][0] + woff[mm]) = pk;
            }
            SYNC_LDS();
        }
    } else if (wid == 2) {
        // ================= u producer =================
        const float* ubase = xwb + (size_t)(b0 + l15) * MHW + mi * HH + g * 4;
#pragma unroll
        for (int q = 0; q < 4; ++q) {  // prologue: slots 0..3
            int t = min(q, Tm - 1) << mi;
            const float* pt = ubase + (size_t)t * BB * MHW;
#pragma unroll
            for (int p = 0; p < 8; ++p)
                gld_lds16(pt + p * 16, &sU[q][0] + p * 1024);
        }
        SYNC_VM24();  // retires slot 0
        for (int K = 0; K < Tm; ++K) {
            int t = min(K + 4, Tm - 1) << mi;
            int slot = (K + 4) & 7;
            const float* pt = ubase + (size_t)t * BB * MHW;
#pragma unroll
            for (int p = 0; p < 8; ++p)
                gld_lds16(pt + p * 16, &sU[slot][0] + p * 1024);
            SYNC_VM24();  // retires slot K+1 (needed next step)
        }
        asm volatile("s_waitcnt vmcnt(0)" ::: "memory");
    } else {
        // ================= h storer =================
        int bq = lane >> 2;
        int rr = (lane & 3) * 32;
        unsigned short* hm =
            hmod + c_hmod_off[mi] + (size_t)(b0 + bq) * HH + rr;
        int soff[4];
#pragma unroll
        for (int c = 0; c < 4; ++c)
            soff[c] = (bq * 256 + (rr + c * 8) * 2) ^ ((bq & 7) << 4);
        SYNC_LDS();
        for (int K = 0; K < Tm; ++K) {
            if (K >= 1) {
                uint4 h[4];
#pragma unroll
                for (int c = 0; c < 4; ++c)
                    h[c] = *reinterpret_cast<const uint4*>(&sH[K & 1][0] + soff[c]);
                unsigned short* dst = hm + (size_t)(K - 1) * BB * HH;
#pragma unroll
                for (int c = 0; c < 4; ++c)
                    *reinterpret_cast<uint4*>(dst + c * 8) = h[c];
            }
            SYNC_LDS();
        }
        {  // final state s_Tm -> hmod[Tm-1]
            uint4 h[4];
#pragma unroll
            for (int c = 0; c < 4; ++c)
                h[c] = *reinterpret_cast<const uint4*>(&sH[Tm & 1][0] + soff[c]);
            unsigned short* dst = hm + (size_t)(Tm - 1) * BB * HH;
#pragma unroll
            for (int c = 0; c < 4; ++c)
                *reinterpret_cast<uint4*>(dst + c * 8) = h[c];
        }
    }
}

// ---------------------------------------------------------------------------
// K_out: out[t][b][j*H + h] = bf2f(Hmod[j][t>>j][b][h]); h_last for t==T-1
// ---------------------------------------------------------------------------
__global__ __launch_bounds__(256) void k_out(const unsigned short* __restrict__ hmod,
                                             float* __restrict__ out) {
    int b = blockIdx.x, t = blockIdx.y;
    int tid = threadIdx.x;
    int i = tid * 4;
    int j = i >> 7;
    int k = t >> j;
    ushort4 h = *reinterpret_cast<const ushort4*>(
        &hmod[c_hmod_off[j] + ((size_t)k * BB + b) * HH + (i & 127)]);
    float4 v = make_float4(bf2f(h.x), bf2f(h.y), bf2f(h.z), bf2f(h.w));
    *reinterpret_cast<float4*>(&out[((size_t)t * BB + b) * MHW + i]) = v;
    if (t == TT - 1) {
        *reinterpret_cast<float4*>(
            &out[(size_t)TT * BB * MHW + (size_t)b * MHW + i]) = v;
    }
}

// ---------------------------------------------------------------------------
extern "C" void kernel_launch(void* const* d_in, const int* in_sizes, int n_in,
                              void* d_out, int out_size, void* d_ws, size_t ws_size,
                              hipStream_t stream) {
    const float* x = (const float*)d_in[0];
    const float* hprev = (const float*)d_in[1];
    const float* Wxh = (const float*)d_in[2];
    const float* Whh = (const float*)d_in[3];
    const float* bh = (const float*)d_in[4];
    float* out = (float*)d_out;

    float* xwb = out;                       // scratch: xW + bh + u
    unsigned short* hmod = (unsigned short*)d_ws;  // bf16, 16.7 MB

    k_xw<<<dim3(2, 256), 256, 0, stream>>>(x, Wxh, bh, xwb);

    for (int mi = 7; mi >= 0; --mi) {
        if (mi < 7)
            k_u<<<dim3(TT >> mi), 256, 0, stream>>>(Whh, hprev, hmod, xwb, mi);
        k_phase<<<8, 256, 0, stream>>>(Whh, hprev, xwb, hmod, mi);
    }

    k_out<<<dim3(128, 256), 256, 0, stream>>>(hmod, out);
}

// Round 10
// 469.733 us; speedup vs baseline: 1.1135x; 1.0290x over previous
//
#include <hip/hip_runtime.h>
#include <hip/hip_bf16.h>

// Clockwork RNN, hierarchical decomposition + bf16 MFMA GEMMs.
// Round 10: k_xw v3 — m97-style GEMM. 1020 uniform blocks, one per
// (active row-tile, t, batch-half). Staging = global_load_lds width16,
// f32-in-LDS double buffer, T2 XOR swizzle via pre-swizzled source addrs,
// f32->bf16 convert fused into fragment reads (cvt_pk on ds_read data).
// k_phase wave-specialized (R8); k_u/k_out unchanged.

#define TT 256
#define BB 128
#define INW 512
#define HH 128
#define MHW 1024

typedef __bf16 bf16x8 __attribute__((ext_vector_type(8)));
typedef __bf16 bf16x4 __attribute__((ext_vector_type(4)));
typedef float f32x4 __attribute__((ext_vector_type(4)));

__constant__ unsigned int c_hmod_off[8] = {
    0u, 4194304u, 6291456u, 7340032u, 7864320u, 8126464u, 8257536u, 8323072u};

__device__ __forceinline__ int active_thr(int t) {
    int ma = (t == 0) ? 8 : min(__ffs(t), 8);
    return ma * HH;
}

__device__ __forceinline__ unsigned short f2bf(float f) {
    union { float f; unsigned int u; } v{f};
    unsigned int r = v.u + 0x7FFFu + ((v.u >> 16) & 1u);  // RNE
    return (unsigned short)(r >> 16);
}
__device__ __forceinline__ unsigned int pack2(float lo, float hi) {
    return (unsigned int)f2bf(lo) | ((unsigned int)f2bf(hi) << 16);
}
__device__ __forceinline__ float bf2f(unsigned short u) {
    union { unsigned int i; float f; } v;
    v.i = ((unsigned int)u) << 16;
    return v.f;
}

__device__ __forceinline__ void gld_lds16(const float* g, char* l) {
    __builtin_amdgcn_global_load_lds(
        (const __attribute__((address_space(1))) void*)g,
        (__attribute__((address_space(3))) void*)l, 16, 0, 0);
}

#define TILE_B 16384  // one [128 rows][64 k] bf16 tile image in LDS

// Batch-load a [128][64] f32 tile: 8 independent float4 per thread.
__device__ __forceinline__ void stage_load(float4 (&v)[8],
                                           const float* __restrict__ src,
                                           int stride, int tid) {
    int k4 = (tid & 15) * 4;
    int r0 = tid >> 4;
#pragma unroll
    for (int p = 0; p < 8; ++p)
        v[p] = *reinterpret_cast<const float4*>(src + (size_t)(p * 16 + r0) * stride + k4);
}

// Convert + write the staged tile into LDS (bf16, XOR-swizzled rows).
__device__ __forceinline__ void stage_write(char* dst, const float4 (&v)[8], int tid) {
    int k8 = (tid & 15) * 8;
    int r0 = tid >> 4;
#pragma unroll
    for (int p = 0; p < 8; ++p) {
        int row = p * 16 + r0;
        ushort4 b;
        b.x = f2bf(v[p].x); b.y = f2bf(v[p].y);
        b.z = f2bf(v[p].z); b.w = f2bf(v[p].w);
        int off = (row * 128 + k8) ^ ((row & 7) << 4);
        *reinterpret_cast<ushort4*>(dst + off) = b;
    }
}

// bf16-source variants: [128 rows][64 k] tile, row stride HH (ushorts).
__device__ __forceinline__ void stage_load_h16(uint4 (&v)[4],
                                               const unsigned short* __restrict__ src,
                                               int tid) {
    int k16 = (tid & 7) * 8;
    int r0 = tid >> 3;
#pragma unroll
    for (int p = 0; p < 4; ++p)
        v[p] = *reinterpret_cast<const uint4*>(src + (size_t)(p * 32 + r0) * HH + k16);
}
__device__ __forceinline__ void stage_write_h16(char* dst, const uint4 (&v)[4], int tid) {
    int k16 = (tid & 7) * 8;
    int r0 = tid >> 3;
#pragma unroll
    for (int p = 0; p < 4; ++p) {
        int row = p * 32 + r0;
        int off = (row * 128 + k16 * 2) ^ ((row & 7) << 4);
        *reinterpret_cast<uint4*>(dst + off) = v[p];
    }
}

// Read one 16x32 bf16 fragment (8 bf16) from a swizzled bf16 tile.
__device__ __forceinline__ bf16x8 frag_ld(const char* tile, int row, int ks, int lane) {
    int off = (row * 128 + ks * 64 + (lane >> 4) * 16) ^ ((row & 7) << 4);
    return *reinterpret_cast<const bf16x8*>(tile + off);
}

// Read one fragment from a swizzled *f32* tile ([rows][64k] f32, 256B/row)
// and convert to bf16x8 (compiler emits v_cvt_pk_bf16_f32).
__device__ __forceinline__ bf16x8 frag_ld_f32(const char* tile, int row, int ks, int g) {
    int off = ((row << 8) + ks * 128 + g * 32) ^ ((row & 7) << 4);
    f32x4 a = *reinterpret_cast<const f32x4*>(tile + off);
    f32x4 b = *reinterpret_cast<const f32x4*>(tile + (off ^ 16));
    bf16x8 u;
    u[0] = (__bf16)a[0]; u[1] = (__bf16)a[1]; u[2] = (__bf16)a[2]; u[3] = (__bf16)a[3];
    u[4] = (__bf16)b[0]; u[5] = (__bf16)b[1]; u[6] = (__bf16)b[2]; u[7] = (__bf16)b[3];
    return u;
}

// 128x128x64 MFMA block: A-tile x B-tile -> acc (4 waves, 64x64 quadrants)
__device__ __forceinline__ void mfma_tile(const char* sA, const char* sB,
                                          f32x4 (&acc)[4][4], int lane,
                                          int wr, int wc) {
#pragma unroll
    for (int ks = 0; ks < 2; ++ks) {
        bf16x8 fa[4], fb[4];
#pragma unroll
        for (int i = 0; i < 4; ++i) {
            fa[i] = frag_ld(sA, wr + i * 16 + (lane & 15), ks, lane);
            fb[i] = frag_ld(sB, wc + i * 16 + (lane & 15), ks, lane);
        }
#pragma unroll
        for (int i = 0; i < 4; ++i)
#pragma unroll
            for (int j = 0; j < 4; ++j)
                acc[i][j] = __builtin_amdgcn_mfma_f32_16x16x32_bf16(
                    fa[i], fb[j], acc[i][j], 0, 0, 0);
    }
}

// ---------------------------------------------------------------------------
// K_xw v3: grid 1020 = 510 active (t, rt) tiles x 2 batch-halves.
// Per block: one 128r x 64b output tile, K=512 in 8 chunks of 64.
// gld_lds f32 staging (W 32KB + x 16KB per buf, dbuf = 96KB LDS),
// pre-swizzled source addresses, cvt-on-read fragments.
// ---------------------------------------------------------------------------
__global__ __launch_bounds__(256) void k_xw(const float* __restrict__ x,
                                            const float* __restrict__ Wxh,
                                            const float* __restrict__ bh,
                                            float* __restrict__ xwb) {
    __shared__ char ldsW[2][32768];
    __shared__ char ldsX[2][16384];
    int id = blockIdx.x >> 1, half = blockIdx.x & 1;
    int rt = 0, rem = id;
    while (rem >= (256 >> rt)) { rem -= 256 >> rt; ++rt; }
    int t = rem << rt;

    int tid = threadIdx.x, lane = tid & 63, wid = tid >> 6;
    int l15 = lane & 15, g = lane >> 4;
    int wr = (wid >> 1) * 64, wc = (wid & 1) * 32;

    // Pre-swizzled per-lane global sources (rule #21: linear dest +
    // inverse-swizzled source + swizzled read).
    const float* gW[8];
    const float* gX[4];
    {
        int kb = (lane & 15) * 16;  // byte offset within 256B row-chunk
#pragma unroll
        for (int i = 0; i < 8; ++i) {
            int row = i * 16 + wid * 4 + (lane >> 4);
            int kf = (kb ^ ((row & 7) << 4)) >> 2;
            gW[i] = Wxh + (size_t)(rt * 128 + row) * INW + kf;
        }
#pragma unroll
        for (int i = 0; i < 4; ++i) {
            int row = i * 16 + wid * 4 + (lane >> 4);
            int kf = (kb ^ ((row & 7) << 4)) >> 2;
            gX[i] = x + ((size_t)t * BB + half * 64 + row) * INW + kf;
        }
    }
    // prologue: stage chunk 0 into buf 0
#pragma unroll
    for (int i = 0; i < 8; ++i)
        gld_lds16(gW[i], &ldsW[0][0] + i * 4096 + wid * 1024);
#pragma unroll
    for (int i = 0; i < 4; ++i)
        gld_lds16(gX[i], &ldsX[0][0] + i * 4096 + wid * 1024);

    f32x4 acc[4][2] = {};
    for (int c = 0; c < 8; ++c) {
        int cur = c & 1;
        __syncthreads();  // buf[cur] ready (drains gld_lds)
        if (c < 7) {
#pragma unroll
            for (int i = 0; i < 8; ++i)
                gld_lds16(gW[i] + (c + 1) * 64,
                          &ldsW[cur ^ 1][0] + i * 4096 + wid * 1024);
#pragma unroll
            for (int i = 0; i < 4; ++i)
                gld_lds16(gX[i] + (c + 1) * 64,
                          &ldsX[cur ^ 1][0] + i * 4096 + wid * 1024);
        }
#pragma unroll
        for (int ks = 0; ks < 2; ++ks) {
            bf16x8 fa[4], fb[2];
#pragma unroll
            for (int i = 0; i < 4; ++i)
                fa[i] = frag_ld_f32(&ldsW[cur][0], wr + i * 16 + l15, ks, g);
#pragma unroll
            for (int j = 0; j < 2; ++j)
                fb[j] = frag_ld_f32(&ldsX[cur][0], wc + j * 16 + l15, ks, g);
#pragma unroll
            for (int i = 0; i < 4; ++i)
#pragma unroll
                for (int j = 0; j < 2; ++j)
                    acc[i][j] = __builtin_amdgcn_mfma_f32_16x16x32_bf16(
                        fa[i], fb[j], acc[i][j], 0, 0, 0);
        }
    }
    // epilogue: bias + store
#pragma unroll
    for (int i = 0; i < 4; ++i) {
        int rbase = rt * 128 + wr + i * 16 + g * 4;
        float4 bias = *reinterpret_cast<const float4*>(&bh[rbase]);
#pragma unroll
        for (int j = 0; j < 2; ++j) {
            int b = half * 64 + wc + j * 16 + l15;
            float4 v = make_float4(acc[i][j][0] + bias.x, acc[i][j][1] + bias.y,
                                   acc[i][j][2] + bias.z, acc[i][j][3] + bias.w);
            *reinterpret_cast<float4*>(
                &xwb[(size_t)(t * BB + b) * MHW + rbase]) = v;
        }
    }
}

// ---------------------------------------------------------------------------
// K_u: xwb[t][b][mi*H+r] += sum_{j>mi} Whh[mi*H+r][j*H+c] * h_j[b][c]
// H source: hprev f32 (k==0) else hmod bf16.
// ---------------------------------------------------------------------------
__global__ __launch_bounds__(256) void k_u(const float* __restrict__ Whh,
                                           const float* __restrict__ hprev,
                                           const unsigned short* __restrict__ hmod,
                                           float* __restrict__ xwb, int mi) {
    int k = blockIdx.x;
    int t = k << mi;
    __shared__ char lds[4 * TILE_B];  // A0 H0 | A1 H1
    int tid = threadIdx.x, lane = tid & 63, wid = tid >> 6;
    int wr = (wid >> 1) * 64, wc = (wid & 1) * 64;

    int ntile = 2 * (7 - mi);
    f32x4 acc[4][4] = {};

    if (k == 0) {
        auto srcs = [&](int tt, const float*& pa, const float*& ph) {
            int j = mi + 1 + (tt >> 1);
            int c0 = (tt & 1) * 64;
            pa = Whh + (size_t)(mi * HH) * MHW + j * HH + c0;
            ph = hprev + j * HH + c0;
        };
        float4 vA[8], vH[8];
        const float *pa, *ph;
        srcs(0, pa, ph);
        stage_load(vA, pa, MHW, tid);
        stage_load(vH, ph, MHW, tid);
        stage_write(lds, vA, tid);
        stage_write(lds + TILE_B, vH, tid);
        for (int tt = 0; tt < ntile; ++tt) {
            int cur = tt & 1;
            __syncthreads();
            if (tt + 1 < ntile) {
                srcs(tt + 1, pa, ph);
                stage_load(vA, pa, MHW, tid);
                stage_load(vH, ph, MHW, tid);
            }
            mfma_tile(lds + cur * 2 * TILE_B, lds + cur * 2 * TILE_B + TILE_B,
                      acc, lane, wr, wc);
            if (tt + 1 < ntile) {
                stage_write(lds + (cur ^ 1) * 2 * TILE_B, vA, tid);
                stage_write(lds + (cur ^ 1) * 2 * TILE_B + TILE_B, vH, tid);
            }
        }
    } else {
        auto srcs = [&](int tt, const float*& pa, const unsigned short*& ph) {
            int j = mi + 1 + (tt >> 1);
            int c0 = (tt & 1) * 64;
            pa = Whh + (size_t)(mi * HH) * MHW + j * HH + c0;
            int g = (t - 1) >> j;
            ph = hmod + c_hmod_off[j] + (size_t)g * BB * HH + c0;
        };
        float4 vA[8];
        uint4 vH[4];
        const float* pa;
        const unsigned short* ph;
        srcs(0, pa, ph);
        stage_load(vA, pa, MHW, tid);
        stage_load_h16(vH, ph, tid);
        stage_write(lds, vA, tid);
        stage_write_h16(lds + TILE_B, vH, tid);
        for (int tt = 0; tt < ntile; ++tt) {
            int cur = tt & 1;
            __syncthreads();
            if (tt + 1 < ntile) {
                srcs(tt + 1, pa, ph);
                stage_load(vA, pa, MHW, tid);
                stage_load_h16(vH, ph, tid);
            }
            mfma_tile(lds + cur * 2 * TILE_B, lds + cur * 2 * TILE_B + TILE_B,
                      acc, lane, wr, wc);
            if (tt + 1 < ntile) {
                stage_write(lds + (cur ^ 1) * 2 * TILE_B, vA, tid);
                stage_write_h16(lds + (cur ^ 1) * 2 * TILE_B + TILE_B, vH, tid);
            }
        }
    }
#pragma unroll
    for (int i = 0; i < 4; ++i) {
        int rbase = wr + i * 16 + (lane >> 4) * 4;
#pragma unroll
        for (int j = 0; j < 4; ++j) {
            int b = wc + j * 16 + (lane & 15);
            float4* p = reinterpret_cast<float4*>(
                &xwb[(size_t)(t * BB + b) * MHW + mi * HH + rbase]);
            float4 v = *p;
            v.x += acc[i][j][0]; v.y += acc[i][j][1];
            v.z += acc[i][j][2]; v.w += acc[i][j][3];
            *p = v;
        }
    }
}

// ---------------------------------------------------------------------------
// K_phase v6: wave-specialized MFMA scan. grid 8 blocks (16 batches each),
// 256 threads = waves {0,1}: compute, 2: u-producer, 3: h-storer.
// ---------------------------------------------------------------------------
#define SYNC_LDS()                                              \
    do {                                                        \
        asm volatile("s_waitcnt lgkmcnt(0)" ::: "memory");      \
        __builtin_amdgcn_sched_barrier(0);                      \
        __builtin_amdgcn_s_barrier();                           \
        __builtin_amdgcn_sched_barrier(0);                      \
    } while (0)
#define SYNC_VM24()                                             \
    do {                                                        \
        asm volatile("s_waitcnt vmcnt(24)" ::: "memory");       \
        __builtin_amdgcn_sched_barrier(0);                      \
        __builtin_amdgcn_s_barrier();                           \
        __builtin_amdgcn_sched_barrier(0);                      \
    } while (0)

__global__ __launch_bounds__(256) void k_phase(const float* __restrict__ Whh,
                                               const float* __restrict__ hprev,
                                               const float* __restrict__ xwb,
                                               unsigned short* __restrict__ hmod,
                                               int mi) {
    int b0 = blockIdx.x * 16;
    int tid = threadIdx.x, lane = tid & 63, wid = tid >> 6;
    int l15 = lane & 15, g = lane >> 4;
    __shared__ char sH[2][4096];   // [buf][b][r] bf16, swizzled
    __shared__ char sU[8][8192];   // u ring: [slot][c=r/4][b][4xf32], linear
    int Tm = TT >> mi;

    if (wid < 2) {
        // ================= compute waves =================
        bf16x8 Af[4][4];
        {
            const float* Ab = Whh + (size_t)(mi * HH) * MHW + mi * HH;
#pragma unroll
            for (int mm = 0; mm < 4; ++mm) {
                const float* row = Ab + (size_t)(64 * wid + mm * 16 + l15) * MHW;
#pragma unroll
                for (int kf = 0; kf < 4; ++kf) {
                    float4 v0 = *reinterpret_cast<const float4*>(row + kf * 32 + g * 8);
                    float4 v1 = *reinterpret_cast<const float4*>(row + kf * 32 + g * 8 + 4);
                    bf16x8 u;
                    u[0] = (__bf16)v0.x; u[1] = (__bf16)v0.y;
                    u[2] = (__bf16)v0.z; u[3] = (__bf16)v0.w;
                    u[4] = (__bf16)v1.x; u[5] = (__bf16)v1.y;
                    u[6] = (__bf16)v1.z; u[7] = (__bf16)v1.w;
                    Af[mm][kf] = u;
                }
            }
        }
        // initial H into buf 0 (tid 0..127 cover 16 batches x 128 rows)
#pragma unroll
        for (int p = 0; p < 2; ++p) {
            int tt = tid + p * 128;
            int b = tt >> 4, r8 = (tt & 15) * 8;
            const float* hp = hprev + (size_t)(b0 + b) * MHW + mi * HH + r8;
            float4 v0 = *reinterpret_cast<const float4*>(hp);
            float4 v1 = *reinterpret_cast<const float4*>(hp + 4);
            uint4 pk;
            pk.x = pack2(v0.x, v0.y); pk.y = pack2(v0.z, v0.w);
            pk.z = pack2(v1.x, v1.y); pk.w = pack2(v1.z, v1.w);
            int off = (b * 256 + r8 * 2) ^ ((b & 7) << 4);
            *reinterpret_cast<uint4*>(&sH[0][0] + off) = pk;
        }
        int roff[4], woff[4], uoff[4];
#pragma unroll
        for (int kf = 0; kf < 4; ++kf)
            roff[kf] = (l15 * 256 + kf * 64 + g * 16) ^ ((l15 & 7) << 4);
#pragma unroll
        for (int mm = 0; mm < 4; ++mm) {
            woff[mm] = (l15 * 256 + (64 * wid + mm * 16 + g * 4) * 2) ^ ((l15 & 7) << 4);
            uoff[mm] = (16 * wid + 4 * mm + g) * 256 + l15 * 16;
        }
        SYNC_LDS();

        for (int K = 0; K < Tm; ++K) {
            int cur = K & 1;
            const char* ub = &sU[K & 7][0];
            f32x4 acc[4], acc2[4];
#pragma unroll
            for (int mm = 0; mm < 4; ++mm) {
                acc[mm] = *reinterpret_cast<const f32x4*>(ub + uoff[mm]);
                acc2[mm] = (f32x4){0.f, 0.f, 0.f, 0.f};
            }
            bf16x8 Bf[4];
#pragma unroll
            for (int kf = 0; kf < 4; ++kf)
                Bf[kf] = *reinterpret_cast<const bf16x8*>(&sH[cur][0] + roff[kf]);
#pragma unroll
            for (int mm = 0; mm < 4; ++mm) {
                acc[mm] = __builtin_amdgcn_mfma_f32_16x16x32_bf16(
                    Af[mm][0], Bf[0], acc[mm], 0, 0, 0);
                acc2[mm] = __builtin_amdgcn_mfma_f32_16x16x32_bf16(
                    Af[mm][2], Bf[2], acc2[mm], 0, 0, 0);
                acc[mm] = __builtin_amdgcn_mfma_f32_16x16x32_bf16(
                    Af[mm][1], Bf[1], acc[mm], 0, 0, 0);
                acc2[mm] = __builtin_amdgcn_mfma_f32_16x16x32_bf16(
                    Af[mm][3], Bf[3], acc2[mm], 0, 0, 0);
            }
#pragma unroll
            for (int mm = 0; mm < 4; ++mm) {
                acc[mm] += acc2[mm];
                bf16x4 pk;
                pk[0] = (__bf16)acc[mm][0]; pk[1] = (__bf16)acc[mm][1];
                pk[2] = (__bf16)acc[mm][2]; pk[3] = (__bf16)acc[mm][3];
                *reinterpret_cast<bf16x4*>(&sH[cur ^ 1][0] + woff[mm]) = pk;
            }
            SYNC_LDS();
        }
    } else if (wid == 2) {
        // ================= u producer =================
        const float* ubase = xwb + (size_t)(b0 + l15) * MHW + mi * HH + g * 4;
#pragma unroll
        for (int q = 0; q < 4; ++q) {  // prologue: slots 0..3
            int t = min(q, Tm - 1) << mi;
            const float* pt = ubase + (size_t)t * BB * MHW;
#pragma unroll
            for (int p = 0; p < 8; ++p)
                gld_lds16(pt + p * 16, &sU[q][0] + p * 1024);
        }
        SYNC_VM24();  // retires slot 0
        for (int K = 0; K < Tm; ++K) {
            int t = min(K + 4, Tm - 1) << mi;
            int slot = (K + 4) & 7;
            const float* pt = ubase + (size_t)t * BB * MHW;
#pragma unroll
            for (int p = 0; p < 8; ++p)
                gld_lds16(pt + p * 16, &sU[slot][0] + p * 1024);
            SYNC_VM24();  // retires slot K+1 (needed next step)
        }
        asm volatile("s_waitcnt vmcnt(0)" ::: "memory");
    } else {
        // ================= h storer =================
        int bq = lane >> 2;
        int rr = (lane & 3) * 32;
        unsigned short* hm =
            hmod + c_hmod_off[mi] + (size_t)(b0 + bq) * HH + rr;
        int soff[4];
#pragma unroll
        for (int c = 0; c < 4; ++c)
            soff[c] = (bq * 256 + (rr + c * 8) * 2) ^ ((bq & 7) << 4);
        SYNC_LDS();
        for (int K = 0; K < Tm; ++K) {
            if (K >= 1) {
                uint4 h[4];
#pragma unroll
                for (int c = 0; c < 4; ++c)
                    h[c] = *reinterpret_cast<const uint4*>(&sH[K & 1][0] + soff[c]);
                unsigned short* dst = hm + (size_t)(K - 1) * BB * HH;
#pragma unroll
                for (int c = 0; c < 4; ++c)
                    *reinterpret_cast<uint4*>(dst + c * 8) = h[c];
            }
            SYNC_LDS();
        }
        {  // final state s_Tm -> hmod[Tm-1]
            uint4 h[4];
#pragma unroll
            for (int c = 0; c < 4; ++c)
                h[c] = *reinterpret_cast<const uint4*>(&sH[Tm & 1][0] + soff[c]);
            unsigned short* dst = hm + (size_t)(Tm - 1) * BB * HH;
#pragma unroll
            for (int c = 0; c < 4; ++c)
                *reinterpret_cast<uint4*>(dst + c * 8) = h[c];
        }
    }
}

// ---------------------------------------------------------------------------
// K_out: out[t][b][j*H + h] = bf2f(Hmod[j][t>>j][b][h]); h_last for t==T-1
// ---------------------------------------------------------------------------
__global__ __launch_bounds__(256) void k_out(const unsigned short* __restrict__ hmod,
                                             float* __restrict__ out) {
    int b = blockIdx.x, t = blockIdx.y;
    int tid = threadIdx.x;
    int i = tid * 4;
    int j = i >> 7;
    int k = t >> j;
    ushort4 h = *reinterpret_cast<const ushort4*>(
        &hmod[c_hmod_off[j] + ((size_t)k * BB + b) * HH + (i & 127)]);
    float4 v = make_float4(bf2f(h.x), bf2f(h.y), bf2f(h.z), bf2f(h.w));
    *reinterpret_cast<float4*>(&out[((size_t)t * BB + b) * MHW + i]) = v;
    if (t == TT - 1) {
        *reinterpret_cast<float4*>(
            &out[(size_t)TT * BB * MHW + (size_t)b * MHW + i]) = v;
    }
}

// ---------------------------------------------------------------------------
extern "C" void kernel_launch(void* const* d_in, const int* in_sizes, int n_in,
                              void* d_out, int out_size, void* d_ws, size_t ws_size,
                              hipStream_t stream) {
    const float* x = (const float*)d_in[0];
    const float* hprev = (const float*)d_in[1];
    const float* Wxh = (const float*)d_in[2];
    const float* Whh = (const float*)d_in[3];
    const float* bh = (const float*)d_in[4];
    float* out = (float*)d_out;

    float* xwb = out;                       // scratch: xW + bh + u
    unsigned short* hmod = (unsigned short*)d_ws;  // bf16, 16.7 MB

    k_xw<<<dim3(1020), 256, 0, stream>>>(x, Wxh, bh, xwb);

    for (int mi = 7; mi >= 0; --mi) {
        if (mi < 7)
            k_u<<<dim3(TT >> mi), 256, 0, stream>>>(Whh, hprev, hmod, xwb, mi);
        k_phase<<<8, 256, 0, stream>>>(Whh, hprev, xwb, hmod, mi);
    }

    k_out<<<dim3(128, 256), 256, 0, stream>>>(hmod, out);
}